// Round 1
// baseline (168.633 us; speedup 1.0000x reference)
//
#include <hip/hip_runtime.h>
#include <math.h>

#define C_DIM 1000
#define BIG   1.0e30f   // pad: u huge -> rcp underflows -> 0 in every sum (self-masking)

__device__ __forceinline__ float fexp2(float x) { return __builtin_amdgcn_exp2f(x); }
__device__ __forceinline__ float flog2(float x) { return __builtin_amdgcn_logf(x); }
__device__ __forceinline__ float frcp(float x)  { return __builtin_amdgcn_rcpf(x); }

// ---- DPP wave64 reductions (VALU pipe) ----
template <int CTRL, int RM>
__device__ __forceinline__ float dpp_add_term(float x) {
    int y = __builtin_amdgcn_update_dpp(0, __float_as_int(x), CTRL, RM, 0xf, true);
    return __int_as_float(y);
}
template <int CTRL, int RM>
__device__ __forceinline__ float dpp_max_term(float x) {
    int y = __builtin_amdgcn_update_dpp(__float_as_int(x), __float_as_int(x), CTRL, RM, 0xf, false);
    return __int_as_float(y);
}

#define DPP_SUM_CHAIN(x)                      \
    x += dpp_add_term<0x111, 0xf>(x);         \
    x += dpp_add_term<0x112, 0xf>(x);         \
    x += dpp_add_term<0x114, 0xf>(x);         \
    x += dpp_add_term<0x118, 0xf>(x);         \
    x += dpp_add_term<0x142, 0xa>(x);         \
    x += dpp_add_term<0x143, 0xc>(x);

__device__ __forceinline__ float bcast63(float x) {
    return __int_as_float(__builtin_amdgcn_readlane(__float_as_int(x), 63));
}

__device__ __forceinline__ float wave_sum(float x) {
    DPP_SUM_CHAIN(x)
    return bcast63(x);
}

__device__ __forceinline__ float wave_max(float x) {
    x = fmaxf(x, dpp_max_term<0x111, 0xf>(x));
    x = fmaxf(x, dpp_max_term<0x112, 0xf>(x));
    x = fmaxf(x, dpp_max_term<0x114, 0xf>(x));
    x = fmaxf(x, dpp_max_term<0x118, 0xf>(x));
    x = fmaxf(x, dpp_max_term<0x142, 0xa>(x));
    x = fmaxf(x, dpp_max_term<0x143, 0xc>(x));
    return bcast63(x);
}

// transform 16 logits -> bb[k] = -0.2*a[k]; returns lane-local max of a
__device__ __forceinline__ float tr16(const float4 x0, const float4 x1,
                                      const float4 x2, const float4 x3,
                                      float bb[16])
{
    bb[0]=-0.2f*x0.x;  bb[1]=-0.2f*x0.y;  bb[2]=-0.2f*x0.z;  bb[3]=-0.2f*x0.w;
    bb[4]=-0.2f*x1.x;  bb[5]=-0.2f*x1.y;  bb[6]=-0.2f*x1.z;  bb[7]=-0.2f*x1.w;
    bb[8]=-0.2f*x2.x;  bb[9]=-0.2f*x2.y;  bb[10]=-0.2f*x2.z; bb[11]=-0.2f*x2.w;
    bb[12]=-0.2f*x3.x; bb[13]=-0.2f*x3.y; bb[14]=-0.2f*x3.z; bb[15]=-0.2f*x3.w;
    float m0 = fmaxf(fmaxf(x0.x, x0.y), fmaxf(x0.z, x0.w));
    float m1 = fmaxf(fmaxf(x1.x, x1.y), fmaxf(x1.z, x1.w));
    float m2 = fmaxf(fmaxf(x2.x, x2.y), fmaxf(x2.z, x2.w));
    float m3 = fmaxf(fmaxf(x3.x, x3.y), fmaxf(x3.z, x3.w));
    return fmaxf(fmaxf(m0, m1), fmaxf(m2, m3));
}

// hot-class dot against bb (targets are raw one-hot {0,1}; ahb = -0.2 * a_hot)
__device__ __forceinline__ float dot16(const float4 t0, const float4 t1,
                                       const float4 t2, const float4 t3,
                                       const float bb[16])
{
    float s = 0.0f;
    s = fmaf(t0.x, bb[0],  s); s = fmaf(t0.y, bb[1],  s);
    s = fmaf(t0.z, bb[2],  s); s = fmaf(t0.w, bb[3],  s);
    s = fmaf(t1.x, bb[4],  s); s = fmaf(t1.y, bb[5],  s);
    s = fmaf(t1.z, bb[6],  s); s = fmaf(t1.w, bb[7],  s);
    s = fmaf(t2.x, bb[8],  s); s = fmaf(t2.y, bb[9],  s);
    s = fmaf(t2.z, bb[10], s); s = fmaf(t2.w, bb[11], s);
    s = fmaf(t3.x, bb[12], s); s = fmaf(t3.y, bb[13], s);
    s = fmaf(t3.z, bb[14], s); s = fmaf(t3.w, bb[15], s);
    return s;
}

// full per-row pipeline after transform: reductions + 2 FP sweeps + Newton/loss sweep
__device__ __forceinline__ void row_core(const float bb[16], float mxl, float ahbl,
                                         float* __restrict__ row_out, int row, int lane,
                                         float C0, float E_off, float dE)
{
    const float mu  = wave_max(mxl);
    const float ahb = wave_sum(ahbl);
    const float g   = 0.2f * mu;
    const float hb  = ahb + g;          // == -0.2*(a_hot - mu) up to 1-2 ulp

    // ---- sweep 1: FP at lam=1 ----
    const float c1 = 1.0f + g;
    float s = 0.0f;
    #pragma unroll
    for (int k = 0; k < 16; ++k) {
        float u = bb[k] + c1;
        float u2 = u * u;
        s += frcp(u2 * u2 * u);
    }
    s = wave_sum(s);
    const float lam = fexp2(-0.2f * flog2(s));

    // ---- sweep 2: FP at lam -> w = s^0.2 (below root; Newton-safe) ----
    const float c2 = fmaf(lam, g, 1.0f);
    s = 0.0f;
    #pragma unroll
    for (int k = 0; k < 16; ++k) {
        float u = fmaf(lam, bb[k], c2);
        float u2 = u * u;
        s += frcp(u2 * u2 * u);
    }
    s = wave_sum(s);
    const float w = fexp2(0.2f * flog2(s));

    // ---- sweep 3: merged Newton + loss sums, 2nd-order corrected to w+delta ----
    const float c3 = w + g;
    float S4 = 0.0f, S5 = 0.0f, S6 = 0.0f, S9 = 0.0f, S10 = 0.0f, S11 = 0.0f;
    #pragma unroll
    for (int k = 0; k < 16; ++k) {
        float r  = frcp(bb[k] + c3);
        float r2 = r * r;
        float r4 = r2 * r2;
        float r5 = r4 * r;
        float r9 = r4 * r5;
        S4  += r4;
        S5  += r5;
        S6  += r5 * r;
        S9  += r9;
        S10 += r5 * r5;
        S11 += r9 * r2;
    }
    DPP_SUM_CHAIN(S4)
    DPP_SUM_CHAIN(S5)
    DPP_SUM_CHAIN(S6)
    DPP_SUM_CHAIN(S9)
    DPP_SUM_CHAIN(S10)
    DPP_SUM_CHAIN(S11)
    S4 = bcast63(S4);  S5 = bcast63(S5);  S6 = bcast63(S6);
    S9 = bcast63(S9);  S10 = bcast63(S10); S11 = bcast63(S11);

    const float d   = (S5 - 1.0f) * 0.2f * frcp(S6);            // Newton step (~5e-3)
    const float w1  = w + d;
    const float d2  = d * d;
    const float S4c = S4 + fmaf(10.0f * d2, S6,  -4.0f * d * S5);   // S4(w1) + O(d^3)
    const float S9c = S9 + fmaf(45.0f * d2, S11, -9.0f * d * S10);  // S9(w1) + O(d^3)
    const float rh  = frcp(w1 + hb);
    const float rh2 = rh * rh;
    const float rh4 = rh2 * rh2;

    const float loss = fmaf(-E_off, S4c,
                       fmaf(-dE, rh4,
                       fmaf(1.0f / 1.8f, S9c, C0)));
    if (lane == 0) row_out[row] = loss;
}

// 2 rows per wave, software-pipelined: row1's loads stream under row0's compute.
// Grid 2048 blocks x 4 waves = exactly 1 resident generation (8 blocks/CU).
__global__ __launch_bounds__(256, 8) void btll(
    const float* __restrict__ inputs, const float* __restrict__ targets,
    float* __restrict__ row_out, int n_rows,
    float C0, float E_off, float dE)
{
    const int lane = threadIdx.x & 63;
    const int wave = threadIdx.x >> 6;
    const int wid  = blockIdx.x * 4 + wave;
    int row0 = wid * 2;
    if (row0 >= n_rows) return;
    int row1 = row0 + 1;
    const bool has1 = row1 < n_rows;
    if (!has1) row1 = row0;   // clamp: loads stay in-bounds; store is skipped

    const float4* in0 = (const float4*)(inputs  + (size_t)row0 * C_DIM);
    const float4* tg0 = (const float4*)(targets + (size_t)row0 * C_DIM);
    const float4* in1 = (const float4*)(inputs  + (size_t)row1 * C_DIM);
    const float4* tg1 = (const float4*)(targets + (size_t)row1 * C_DIM);
    const bool m3 = (lane + 192) < 250;   // only the 4th chunk needs tail masking
    const float4 xpad = make_float4(-BIG, -BIG, -BIG, -BIG);
    const float4 tpad = make_float4(0.f, 0.f, 0.f, 0.f);

    // ---- prologue: row0 x+t and row1 x in flight (12 loads) ----
    float4 a0 = in0[lane];
    float4 a1 = in0[lane + 64];
    float4 a2 = in0[lane + 128];
    float4 a3 = m3 ? in0[lane + 192] : xpad;
    float4 t0 = tg0[lane];
    float4 t1 = tg0[lane + 64];
    float4 t2 = tg0[lane + 128];
    float4 t3 = m3 ? tg0[lane + 192] : tpad;
    float4 p0 = in1[lane];
    float4 p1 = in1[lane + 64];
    float4 p2 = in1[lane + 128];
    float4 p3 = m3 ? in1[lane + 192] : xpad;

    // row0 transform: a dies into bbA, t dies into ahA
    float bbA[16];
    float mxA = tr16(a0, a1, a2, a3, bbA);
    float ahA = dot16(t0, t1, t2, t3, bbA);

    // issue row1 targets now (t registers free)
    float4 q0 = tg1[lane];
    float4 q1 = tg1[lane + 64];
    float4 q2 = tg1[lane + 128];
    float4 q3 = m3 ? tg1[lane + 192] : tpad;

    // row1 transform early: shrinks row1 live state from 32 regs to 18
    float bbB[16];
    float mxB = tr16(p0, p1, p2, p3, bbB);
    float ahB = dot16(q0, q1, q2, q3, bbB);

    // row0 compute (row1 state fully resident, zero memory waits afterwards)
    row_core(bbA, mxA, ahA, row_out, row0, lane, C0, E_off, dE);
    // row1 compute
    if (has1) row_core(bbB, mxB, ahB, row_out, row1, lane, C0, E_off, dE);
}

__global__ __launch_bounds__(1024) void reduce_mean(
    const float* __restrict__ row_out, float* __restrict__ out, int n)
{
    __shared__ double sm[16];
    const int lane = threadIdx.x & 63;
    const int wv   = threadIdx.x >> 6;
    const int n4   = n >> 2;
    const float4* r4 = (const float4*)row_out;
    double s = 0.0;
    for (int i = threadIdx.x; i < n4; i += 1024) {
        float4 v = r4[i];
        s += (double)v.x + (double)v.y + (double)v.z + (double)v.w;
    }
    if (threadIdx.x == 0)
        for (int i = n4 << 2; i < n; ++i) s += (double)row_out[i];
    #pragma unroll
    for (int off = 32; off > 0; off >>= 1) s += __shfl_xor(s, off, 64);
    if (lane == 0) sm[wv] = s;
    __syncthreads();
    if (wv == 0) {
        double t = (lane < 16) ? sm[lane] : 0.0;
        #pragma unroll
        for (int off = 32; off > 0; off >>= 1) t += __shfl_xor(t, off, 64);
        if (lane == 0) out[0] = (float)(t / (double)n);
    }
}

extern "C" void kernel_launch(void* const* d_in, const int* in_sizes, int n_in,
                              void* d_out, int out_size, void* d_ws, size_t ws_size,
                              hipStream_t stream) {
    const float* inputs  = (const float*)d_in[0];
    const float* targets = (const float*)d_in[1];
    float* out = (float*)d_out;

    const int N = in_sizes[0] / C_DIM;
    float* row_out = (float*)d_ws;

    // Smoothed one-hot targets take 2 values; per-elem loss = F - E*r4 + r9/1.8.
    // Row sum = C0 - E_off*S4 - (E_on-E_off)*r4_hot + S9/1.8, C0 = 999*F_off + F_on.
    const double ls    = 0.05;
    const double c1g_d = 1.0 - (1000.0 / 999.0) * ls;
    const double c2_d  = ls / 999.0;
    const float  tp_on_f  = (float)c1g_d + (float)c2_d;
    const float  tp_off_f = (float)c2_d;
    const double tp_on  = (double)tp_on_f;
    const double tp_off = (double)tp_off_f;
    const double A_on  = (pow(tp_on  + 1e-8, 0.8) - 1.0) / 0.8;
    const double A_off = (pow(tp_off + 1e-8, 0.8) - 1.0) / 0.8;
    const double B_on  = pow(tp_on,  1.8);
    const double B_off = pow(tp_off, 1.8);
    const double E_on_d  = 1.25 * tp_on;
    const double E_off_d = 1.25 * tp_off;
    const double F_on_d  = tp_on  * A_on  + E_on_d  - B_on  / 1.8;
    const double F_off_d = tp_off * A_off + E_off_d - B_off / 1.8;
    const double C0_d    = (C_DIM - 1) * F_off_d + F_on_d;
    const double dE_d    = E_on_d - E_off_d;

    dim3 grid((N + 7) / 8);
    btll<<<grid, 256, 0, stream>>>(inputs, targets, row_out, N,
                                   (float)C0_d, (float)E_off_d, (float)dE_d);
    reduce_mean<<<1, 1024, 0, stream>>>(row_out, out, N);
}

// Round 2
// 148.553 us; speedup vs baseline: 1.1352x; 1.1352x over previous
//
#include <hip/hip_runtime.h>
#include <math.h>

#define C_DIM 1000
#define BIG   1.0e30f   // pad: u huge -> rcp underflows -> 0 in every sum (self-masking)

__device__ __forceinline__ float fexp2(float x) { return __builtin_amdgcn_exp2f(x); }
__device__ __forceinline__ float flog2(float x) { return __builtin_amdgcn_logf(x); }
__device__ __forceinline__ float frcp(float x)  { return __builtin_amdgcn_rcpf(x); }

// ---- DPP wave64 reductions (VALU pipe) ----
template <int CTRL, int RM>
__device__ __forceinline__ float dpp_add_term(float x) {
    int y = __builtin_amdgcn_update_dpp(0, __float_as_int(x), CTRL, RM, 0xf, true);
    return __int_as_float(y);
}
template <int CTRL, int RM>
__device__ __forceinline__ float dpp_max_term(float x) {
    int y = __builtin_amdgcn_update_dpp(__float_as_int(x), __float_as_int(x), CTRL, RM, 0xf, false);
    return __int_as_float(y);
}

#define DPP_SUM_CHAIN(x)                      \
    x += dpp_add_term<0x111, 0xf>(x);         \
    x += dpp_add_term<0x112, 0xf>(x);         \
    x += dpp_add_term<0x114, 0xf>(x);         \
    x += dpp_add_term<0x118, 0xf>(x);         \
    x += dpp_add_term<0x142, 0xa>(x);         \
    x += dpp_add_term<0x143, 0xc>(x);

__device__ __forceinline__ float bcast63(float x) {
    return __int_as_float(__builtin_amdgcn_readlane(__float_as_int(x), 63));
}

__device__ __forceinline__ float wave_sum(float x) {
    DPP_SUM_CHAIN(x)
    return bcast63(x);
}

__device__ __forceinline__ float wave_max(float x) {
    x = fmaxf(x, dpp_max_term<0x111, 0xf>(x));
    x = fmaxf(x, dpp_max_term<0x112, 0xf>(x));
    x = fmaxf(x, dpp_max_term<0x114, 0xf>(x));
    x = fmaxf(x, dpp_max_term<0x118, 0xf>(x));
    x = fmaxf(x, dpp_max_term<0x142, 0xa>(x));
    x = fmaxf(x, dpp_max_term<0x143, 0xc>(x));
    return bcast63(x);
}

// transform 16 logits -> bb[k] = -0.2*a[k]; returns lane-local max of a
__device__ __forceinline__ float tr16(const float4 x0, const float4 x1,
                                      const float4 x2, const float4 x3,
                                      float bb[16])
{
    bb[0]=-0.2f*x0.x;  bb[1]=-0.2f*x0.y;  bb[2]=-0.2f*x0.z;  bb[3]=-0.2f*x0.w;
    bb[4]=-0.2f*x1.x;  bb[5]=-0.2f*x1.y;  bb[6]=-0.2f*x1.z;  bb[7]=-0.2f*x1.w;
    bb[8]=-0.2f*x2.x;  bb[9]=-0.2f*x2.y;  bb[10]=-0.2f*x2.z; bb[11]=-0.2f*x2.w;
    bb[12]=-0.2f*x3.x; bb[13]=-0.2f*x3.y; bb[14]=-0.2f*x3.z; bb[15]=-0.2f*x3.w;
    float m0 = fmaxf(fmaxf(x0.x, x0.y), fmaxf(x0.z, x0.w));
    float m1 = fmaxf(fmaxf(x1.x, x1.y), fmaxf(x1.z, x1.w));
    float m2 = fmaxf(fmaxf(x2.x, x2.y), fmaxf(x2.z, x2.w));
    float m3 = fmaxf(fmaxf(x3.x, x3.y), fmaxf(x3.z, x3.w));
    return fmaxf(fmaxf(m0, m1), fmaxf(m2, m3));
}

// hot-class dot against bb (targets are raw one-hot {0,1}; result = -0.2 * a_hot)
__device__ __forceinline__ float dot16(const float4 t0, const float4 t1,
                                       const float4 t2, const float4 t3,
                                       const float bb[16])
{
    float s = 0.0f;
    s = fmaf(t0.x, bb[0],  s); s = fmaf(t0.y, bb[1],  s);
    s = fmaf(t0.z, bb[2],  s); s = fmaf(t0.w, bb[3],  s);
    s = fmaf(t1.x, bb[4],  s); s = fmaf(t1.y, bb[5],  s);
    s = fmaf(t1.z, bb[6],  s); s = fmaf(t1.w, bb[7],  s);
    s = fmaf(t2.x, bb[8],  s); s = fmaf(t2.y, bb[9],  s);
    s = fmaf(t2.z, bb[10], s); s = fmaf(t2.w, bb[11], s);
    s = fmaf(t3.x, bb[12], s); s = fmaf(t3.y, bb[13], s);
    s = fmaf(t3.z, bb[14], s); s = fmaf(t3.w, bb[15], s);
    return s;
}

// full per-row pipeline after transform: reductions + 2 FP sweeps + Newton/loss sweep
__device__ __forceinline__ void row_core(const float bb[16], float mxl, float ahbl,
                                         float* __restrict__ row_out, int row, int lane,
                                         bool st, float C0, float E_off, float dE)
{
    const float mu  = wave_max(mxl);
    const float ahb = wave_sum(ahbl);
    const float g   = 0.2f * mu;
    const float hb  = ahb + g;          // == -0.2*(a_hot - mu) up to 1-2 ulp

    // ---- sweep 1: FP at lam=1 ----
    const float c1 = 1.0f + g;
    float s = 0.0f;
    #pragma unroll
    for (int k = 0; k < 16; ++k) {
        float u = bb[k] + c1;
        float u2 = u * u;
        s += frcp(u2 * u2 * u);
    }
    s = wave_sum(s);
    const float lam = fexp2(-0.2f * flog2(s));

    // ---- sweep 2: FP at lam -> w = s^0.2 (below root; Newton-safe) ----
    const float c2 = fmaf(lam, g, 1.0f);
    s = 0.0f;
    #pragma unroll
    for (int k = 0; k < 16; ++k) {
        float u = fmaf(lam, bb[k], c2);
        float u2 = u * u;
        s += frcp(u2 * u2 * u);
    }
    s = wave_sum(s);
    const float w = fexp2(0.2f * flog2(s));

    // ---- sweep 3: merged Newton + loss sums, 2nd-order corrected to w+delta ----
    const float c3 = w + g;
    float S4 = 0.0f, S5 = 0.0f, S6 = 0.0f, S9 = 0.0f, S10 = 0.0f, S11 = 0.0f;
    #pragma unroll
    for (int k = 0; k < 16; ++k) {
        float r  = frcp(bb[k] + c3);
        float r2 = r * r;
        float r4 = r2 * r2;
        float r5 = r4 * r;
        float r9 = r4 * r5;
        S4  += r4;
        S5  += r5;
        S6  += r5 * r;
        S9  += r9;
        S10 += r5 * r5;
        S11 += r9 * r2;
    }
    DPP_SUM_CHAIN(S4)
    DPP_SUM_CHAIN(S5)
    DPP_SUM_CHAIN(S6)
    DPP_SUM_CHAIN(S9)
    DPP_SUM_CHAIN(S10)
    DPP_SUM_CHAIN(S11)
    S4 = bcast63(S4);  S5 = bcast63(S5);  S6 = bcast63(S6);
    S9 = bcast63(S9);  S10 = bcast63(S10); S11 = bcast63(S11);

    const float d   = (S5 - 1.0f) * 0.2f * frcp(S6);            // Newton step (~5e-3)
    const float w1  = w + d;
    const float d2  = d * d;
    const float S4c = S4 + fmaf(10.0f * d2, S6,  -4.0f * d * S5);   // S4(w1) + O(d^3)
    const float S9c = S9 + fmaf(45.0f * d2, S11, -9.0f * d * S10);  // S9(w1) + O(d^3)
    const float rh  = frcp(w1 + hb);
    const float rh2 = rh * rh;
    const float rh4 = rh2 * rh2;

    const float loss = fmaf(-E_off, S4c,
                       fmaf(-dE, rh4,
                       fmaf(1.0f / 1.8f, S9c, C0)));
    if (st && lane == 0) row_out[row] = loss;
}

// 4 rows per wave, software-pipelined: row i+1's loads stream under row i's
// ~1500-cycle core. Grid 1024 blocks x 4 waves; __launch_bounds__(256,4)
// (128 VGPR budget -- round-1's (256,8) forced 64 and spilled 50 MB to scratch)
// -> 4 resident blocks/CU = exactly ONE generation, prologue stall paid once.
__global__ __launch_bounds__(256, 4) void btll(
    const float* __restrict__ inputs, const float* __restrict__ targets,
    float* __restrict__ row_out, int n_rows,
    float C0, float E_off, float dE)
{
    const int lane = threadIdx.x & 63;
    const int wave = threadIdx.x >> 6;
    const int wid  = blockIdx.x * 4 + wave;
    const int rbase = wid * 4;
    if (rbase >= n_rows) return;

    const int r0 = rbase;
    const int r1 = min(rbase + 1, n_rows - 1);
    const int r2 = min(rbase + 2, n_rows - 1);
    const int r3 = min(rbase + 3, n_rows - 1);
    const bool st1 = (rbase + 1) < n_rows;
    const bool st2 = (rbase + 2) < n_rows;
    const bool st3 = (rbase + 3) < n_rows;

    const float4* in0 = (const float4*)(inputs  + (size_t)r0 * C_DIM);
    const float4* tg0 = (const float4*)(targets + (size_t)r0 * C_DIM);
    const float4* in1 = (const float4*)(inputs  + (size_t)r1 * C_DIM);
    const float4* tg1 = (const float4*)(targets + (size_t)r1 * C_DIM);
    const float4* in2 = (const float4*)(inputs  + (size_t)r2 * C_DIM);
    const float4* tg2 = (const float4*)(targets + (size_t)r2 * C_DIM);
    const float4* in3 = (const float4*)(inputs  + (size_t)r3 * C_DIM);
    const float4* tg3 = (const float4*)(targets + (size_t)r3 * C_DIM);

    const bool m3 = (lane + 192) < 250;   // only the 4th chunk needs tail masking
    const float4 xpad = make_float4(-BIG, -BIG, -BIG, -BIG);
    const float4 tpad = make_float4(0.f, 0.f, 0.f, 0.f);

    // ---- prologue: row0 x+t and row1 x in flight ----
    float4 a0 = in0[lane];
    float4 a1 = in0[lane + 64];
    float4 a2 = in0[lane + 128];
    float4 a3 = m3 ? in0[lane + 192] : xpad;
    float4 t0 = tg0[lane];
    float4 t1 = tg0[lane + 64];
    float4 t2 = tg0[lane + 128];
    float4 t3 = m3 ? tg0[lane + 192] : tpad;
    float4 p0 = in1[lane];
    float4 p1 = in1[lane + 64];
    float4 p2 = in1[lane + 128];
    float4 p3 = m3 ? in1[lane + 192] : xpad;

    float bbA[16], bbB[16];
    float mx, ah;

    // row0 transform (a,t die), then issue row1 targets into the freed t regs
    mx = tr16(a0, a1, a2, a3, bbA);
    ah = dot16(t0, t1, t2, t3, bbA);
    t0 = tg1[lane];
    t1 = tg1[lane + 64];
    t2 = tg1[lane + 128];
    t3 = m3 ? tg1[lane + 192] : tpad;

    // row0 core: row1's x(p) + t loads land underneath (~1500 cy compute > ~900 cy HBM)
    row_core(bbA, mx, ah, row_out, r0, lane, true, C0, E_off, dE);

    // row1 transform, then issue row2 loads into freed p,t regs
    mx = tr16(p0, p1, p2, p3, bbB);
    ah = dot16(t0, t1, t2, t3, bbB);
    p0 = in2[lane];
    p1 = in2[lane + 64];
    p2 = in2[lane + 128];
    p3 = m3 ? in2[lane + 192] : xpad;
    t0 = tg2[lane];
    t1 = tg2[lane + 64];
    t2 = tg2[lane + 128];
    t3 = m3 ? tg2[lane + 192] : tpad;

    row_core(bbB, mx, ah, row_out, r1, lane, st1, C0, E_off, dE);

    // row2 transform, then issue row3 loads
    mx = tr16(p0, p1, p2, p3, bbA);
    ah = dot16(t0, t1, t2, t3, bbA);
    p0 = in3[lane];
    p1 = in3[lane + 64];
    p2 = in3[lane + 128];
    p3 = m3 ? in3[lane + 192] : xpad;
    t0 = tg3[lane];
    t1 = tg3[lane + 64];
    t2 = tg3[lane + 128];
    t3 = m3 ? tg3[lane + 192] : tpad;

    row_core(bbA, mx, ah, row_out, r2, lane, st2, C0, E_off, dE);

    // row3
    mx = tr16(p0, p1, p2, p3, bbB);
    ah = dot16(t0, t1, t2, t3, bbB);
    row_core(bbB, mx, ah, row_out, r3, lane, st3, C0, E_off, dE);
}

__global__ __launch_bounds__(1024) void reduce_mean(
    const float* __restrict__ row_out, float* __restrict__ out, int n)
{
    __shared__ double sm[16];
    const int lane = threadIdx.x & 63;
    const int wv   = threadIdx.x >> 6;
    const int n4   = n >> 2;
    const float4* r4 = (const float4*)row_out;
    double s = 0.0;
    for (int i = threadIdx.x; i < n4; i += 1024) {
        float4 v = r4[i];
        s += (double)v.x + (double)v.y + (double)v.z + (double)v.w;
    }
    if (threadIdx.x == 0)
        for (int i = n4 << 2; i < n; ++i) s += (double)row_out[i];
    #pragma unroll
    for (int off = 32; off > 0; off >>= 1) s += __shfl_xor(s, off, 64);
    if (lane == 0) sm[wv] = s;
    __syncthreads();
    if (wv == 0) {
        double t = (lane < 16) ? sm[lane] : 0.0;
        #pragma unroll
        for (int off = 32; off > 0; off >>= 1) t += __shfl_xor(t, off, 64);
        if (lane == 0) out[0] = (float)(t / (double)n);
    }
}

extern "C" void kernel_launch(void* const* d_in, const int* in_sizes, int n_in,
                              void* d_out, int out_size, void* d_ws, size_t ws_size,
                              hipStream_t stream) {
    const float* inputs  = (const float*)d_in[0];
    const float* targets = (const float*)d_in[1];
    float* out = (float*)d_out;

    const int N = in_sizes[0] / C_DIM;
    float* row_out = (float*)d_ws;

    // Smoothed one-hot targets take 2 values; per-elem loss = F - E*r4 + r9/1.8.
    // Row sum = C0 - E_off*S4 - (E_on-E_off)*r4_hot + S9/1.8, C0 = 999*F_off + F_on.
    const double ls    = 0.05;
    const double c1g_d = 1.0 - (1000.0 / 999.0) * ls;
    const double c2_d  = ls / 999.0;
    const float  tp_on_f  = (float)c1g_d + (float)c2_d;
    const float  tp_off_f = (float)c2_d;
    const double tp_on  = (double)tp_on_f;
    const double tp_off = (double)tp_off_f;
    const double A_on  = (pow(tp_on  + 1e-8, 0.8) - 1.0) / 0.8;
    const double A_off = (pow(tp_off + 1e-8, 0.8) - 1.0) / 0.8;
    const double B_on  = pow(tp_on,  1.8);
    const double B_off = pow(tp_off, 1.8);
    const double E_on_d  = 1.25 * tp_on;
    const double E_off_d = 1.25 * tp_off;
    const double F_on_d  = tp_on  * A_on  + E_on_d  - B_on  / 1.8;
    const double F_off_d = tp_off * A_off + E_off_d - B_off / 1.8;
    const double C0_d    = (C_DIM - 1) * F_off_d + F_on_d;
    const double dE_d    = E_on_d - E_off_d;

    dim3 grid((N + 15) / 16);
    btll<<<grid, 256, 0, stream>>>(inputs, targets, row_out, N,
                                   (float)C0_d, (float)E_off_d, (float)dE_d);
    reduce_mean<<<1, 1024, 0, stream>>>(row_out, out, N);
}

// Round 3
// 146.478 us; speedup vs baseline: 1.1512x; 1.0142x over previous
//
#include <hip/hip_runtime.h>
#include <math.h>
#include <stdint.h>

#define C_DIM 1000
#define BIG   1.0e30f   // pad: u huge -> rcp underflows -> 0 in every sum (self-masking)

typedef float fx4 __attribute__((ext_vector_type(4)));

typedef __attribute__((address_space(1))) void g_void;   // global
typedef __attribute__((address_space(3))) void l_void;   // LDS

__device__ __forceinline__ float fexp2(float x) { return __builtin_amdgcn_exp2f(x); }
__device__ __forceinline__ float flog2(float x) { return __builtin_amdgcn_logf(x); }
__device__ __forceinline__ float frcp(float x)  { return __builtin_amdgcn_rcpf(x); }

// async global->LDS, 16B/lane, dest = uniform base + lane*16 (zero VGPR in flight)
__device__ __forceinline__ void gll16(const float* g, float* l) {
    __builtin_amdgcn_global_load_lds((g_void*)g, (l_void*)l, 16, 0, 0);
}

// ---- DPP wave64 reductions (VALU pipe) ----
template <int CTRL, int RM>
__device__ __forceinline__ float dpp_add_term(float x) {
    int y = __builtin_amdgcn_update_dpp(0, __float_as_int(x), CTRL, RM, 0xf, true);
    return __int_as_float(y);
}
template <int CTRL, int RM>
__device__ __forceinline__ float dpp_max_term(float x) {
    int y = __builtin_amdgcn_update_dpp(__float_as_int(x), __float_as_int(x), CTRL, RM, 0xf, false);
    return __int_as_float(y);
}

#define DPP_SUM_CHAIN(x)                      \
    x += dpp_add_term<0x111, 0xf>(x);         \
    x += dpp_add_term<0x112, 0xf>(x);         \
    x += dpp_add_term<0x114, 0xf>(x);         \
    x += dpp_add_term<0x118, 0xf>(x);         \
    x += dpp_add_term<0x142, 0xa>(x);         \
    x += dpp_add_term<0x143, 0xc>(x);

__device__ __forceinline__ float bcast63(float x) {
    return __int_as_float(__builtin_amdgcn_readlane(__float_as_int(x), 63));
}

__device__ __forceinline__ float wave_sum(float x) {
    DPP_SUM_CHAIN(x)
    return bcast63(x);
}

__device__ __forceinline__ float wave_max(float x) {
    x = fmaxf(x, dpp_max_term<0x111, 0xf>(x));
    x = fmaxf(x, dpp_max_term<0x112, 0xf>(x));
    x = fmaxf(x, dpp_max_term<0x114, 0xf>(x));
    x = fmaxf(x, dpp_max_term<0x118, 0xf>(x));
    x = fmaxf(x, dpp_max_term<0x142, 0xa>(x));
    x = fmaxf(x, dpp_max_term<0x143, 0xc>(x));
    return bcast63(x);
}

// transform 16 logits -> bb[k] = -0.2*a[k]; returns lane-local max of a
__device__ __forceinline__ float tr16(const fx4 x0, const fx4 x1,
                                      const fx4 x2, const fx4 x3,
                                      float bb[16])
{
    bb[0]=-0.2f*x0.x;  bb[1]=-0.2f*x0.y;  bb[2]=-0.2f*x0.z;  bb[3]=-0.2f*x0.w;
    bb[4]=-0.2f*x1.x;  bb[5]=-0.2f*x1.y;  bb[6]=-0.2f*x1.z;  bb[7]=-0.2f*x1.w;
    bb[8]=-0.2f*x2.x;  bb[9]=-0.2f*x2.y;  bb[10]=-0.2f*x2.z; bb[11]=-0.2f*x2.w;
    bb[12]=-0.2f*x3.x; bb[13]=-0.2f*x3.y; bb[14]=-0.2f*x3.z; bb[15]=-0.2f*x3.w;
    float m0 = fmaxf(fmaxf(x0.x, x0.y), fmaxf(x0.z, x0.w));
    float m1 = fmaxf(fmaxf(x1.x, x1.y), fmaxf(x1.z, x1.w));
    float m2 = fmaxf(fmaxf(x2.x, x2.y), fmaxf(x2.z, x2.w));
    float m3 = fmaxf(fmaxf(x3.x, x3.y), fmaxf(x3.z, x3.w));
    return fmaxf(fmaxf(m0, m1), fmaxf(m2, m3));
}

// hot-class dot against bb (targets are raw one-hot {0,1}; result = -0.2 * a_hot)
__device__ __forceinline__ float dot16(const fx4 t0, const fx4 t1,
                                       const fx4 t2, const fx4 t3,
                                       const float bb[16])
{
    float s = 0.0f;
    s = fmaf(t0.x, bb[0],  s); s = fmaf(t0.y, bb[1],  s);
    s = fmaf(t0.z, bb[2],  s); s = fmaf(t0.w, bb[3],  s);
    s = fmaf(t1.x, bb[4],  s); s = fmaf(t1.y, bb[5],  s);
    s = fmaf(t1.z, bb[6],  s); s = fmaf(t1.w, bb[7],  s);
    s = fmaf(t2.x, bb[8],  s); s = fmaf(t2.y, bb[9],  s);
    s = fmaf(t2.z, bb[10], s); s = fmaf(t2.w, bb[11], s);
    s = fmaf(t3.x, bb[12], s); s = fmaf(t3.y, bb[13], s);
    s = fmaf(t3.z, bb[14], s); s = fmaf(t3.w, bb[15], s);
    return s;
}

// full per-row pipeline after transform: reductions + 2 FP sweeps + Newton/loss sweep
__device__ __forceinline__ void row_core(const float bb[16], float mxl, float ahbl,
                                         float* __restrict__ row_out, int row, int lane,
                                         bool st, float C0, float E_off, float dE)
{
    const float mu  = wave_max(mxl);
    const float ahb = wave_sum(ahbl);
    const float g   = 0.2f * mu;
    const float hb  = ahb + g;          // == -0.2*(a_hot - mu) up to 1-2 ulp

    // ---- sweep 1: FP at lam=1 ----
    const float c1 = 1.0f + g;
    float s = 0.0f;
    #pragma unroll
    for (int k = 0; k < 16; ++k) {
        float u = bb[k] + c1;
        float u2 = u * u;
        s += frcp(u2 * u2 * u);
    }
    s = wave_sum(s);
    const float lam = fexp2(-0.2f * flog2(s));

    // ---- sweep 2: FP at lam -> w = s^0.2 (below root; Newton-safe) ----
    const float c2 = fmaf(lam, g, 1.0f);
    s = 0.0f;
    #pragma unroll
    for (int k = 0; k < 16; ++k) {
        float u = fmaf(lam, bb[k], c2);
        float u2 = u * u;
        s += frcp(u2 * u2 * u);
    }
    s = wave_sum(s);
    const float w = fexp2(0.2f * flog2(s));

    // ---- sweep 3: merged Newton + loss sums, 2nd-order corrected to w+delta ----
    const float c3 = w + g;
    float S4 = 0.0f, S5 = 0.0f, S6 = 0.0f, S9 = 0.0f, S10 = 0.0f, S11 = 0.0f;
    #pragma unroll
    for (int k = 0; k < 16; ++k) {
        float r  = frcp(bb[k] + c3);
        float r2 = r * r;
        float r4 = r2 * r2;
        float r5 = r4 * r;
        float r9 = r4 * r5;
        S4  += r4;
        S5  += r5;
        S6  += r5 * r;
        S9  += r9;
        S10 += r5 * r5;
        S11 += r9 * r2;
    }
    DPP_SUM_CHAIN(S4)
    DPP_SUM_CHAIN(S5)
    DPP_SUM_CHAIN(S6)
    DPP_SUM_CHAIN(S9)
    DPP_SUM_CHAIN(S10)
    DPP_SUM_CHAIN(S11)
    S4 = bcast63(S4);  S5 = bcast63(S5);  S6 = bcast63(S6);
    S9 = bcast63(S9);  S10 = bcast63(S10); S11 = bcast63(S11);

    const float d   = (S5 - 1.0f) * 0.2f * frcp(S6);            // Newton step (~5e-3)
    const float w1  = w + d;
    const float d2  = d * d;
    const float S4c = S4 + fmaf(10.0f * d2, S6,  -4.0f * d * S5);   // S4(w1) + O(d^3)
    const float S9c = S9 + fmaf(45.0f * d2, S11, -9.0f * d * S10);  // S9(w1) + O(d^3)
    const float rh  = frcp(w1 + hb);
    const float rh2 = rh * rh;
    const float rh4 = rh2 * rh2;

    const float loss = fmaf(-E_off, S4c,
                       fmaf(-dE, rh4,
                       fmaf(1.0f / 1.8f, S9c, C0)));
    if (st && lane == 0) row_out[row] = loss;
}

// 2 rows/wave, HW-enforced pipeline:
//  - row targets prefetched to a private 4KB LDS buffer via global_load_lds
//    (zero VGPR in flight -> the register-pressure scheduler can't sink them;
//    R2 proved plain loads get sunk: VGPR=48 under a 128 cap)
//  - row1 inputs via asm volatile global_load_dwordx4 + counted s_waitcnt vmcnt(1)
//    with "+v" passthrough (data-dep -> consumers can't hoist; store excluded)
// (256,8): 64 VGPR cap (peak live ~55), 16KB LDS/block -> 8 blocks/CU,
// grid 2048 = exactly ONE generation at 32 waves/CU.
__global__ __launch_bounds__(256, 8) void btll(
    const float* __restrict__ inputs, const float* __restrict__ targets,
    float* __restrict__ row_out, int n_rows,
    float C0, float E_off, float dE)
{
    const int lane = threadIdx.x & 63;
    const int wave = threadIdx.x >> 6;
    const int wid  = blockIdx.x * 4 + wave;
    const int r0i  = wid * 2;
    if (r0i >= n_rows) return;
    int r1i = r0i + 1;
    const bool st1 = r1i < n_rows;
    if (!st1) r1i = r0i;

    __shared__ __align__(16) float ldsT[4][1024];
    float* lt = &ldsT[wave][0];

    const float* in0 = inputs  + (size_t)r0i * C_DIM;
    const float* tg0 = targets + (size_t)r0i * C_DIM;
    const float* in1 = inputs  + (size_t)r1i * C_DIM;
    const float* tg1 = targets + (size_t)r1i * C_DIM;

    const bool m3 = lane < 58;                  // 4th chunk tail mask (250 float4/row)
    const int  o3 = m3 ? (768 + 4 * lane) : 0;  // clamped in-bounds offset for tail
    const fx4  xpad = (fx4){-BIG, -BIG, -BIG, -BIG};
    const fx4  zero = (fx4){0.f, 0.f, 0.f, 0.f};

    // ---- prologue: row0 inputs -> regs, row0 targets -> LDS ----
    fx4 x0 = *(const fx4*)(in0 + 4 * lane);
    fx4 x1 = *(const fx4*)(in0 + 256 + 4 * lane);
    fx4 x2 = *(const fx4*)(in0 + 512 + 4 * lane);
    fx4 x3 = *(const fx4*)(in0 + o3);
    gll16(tg0 + 4 * lane,       lt);
    gll16(tg0 + 256 + 4 * lane, lt + 256);
    gll16(tg0 + 512 + 4 * lane, lt + 512);
    gll16(tg0 + o3,             lt + 768);

    x3 = m3 ? x3 : xpad;
    float bbA[16], bbB[16];
    float mx = tr16(x0, x1, x2, x3, bbA);

    asm volatile("s_waitcnt vmcnt(0)" ::: "memory");   // targets landed in LDS
    fx4 tv0 = *(const fx4*)(lt + 4 * lane);
    fx4 tv1 = *(const fx4*)(lt + 256 + 4 * lane);
    fx4 tv2 = *(const fx4*)(lt + 512 + 4 * lane);
    fx4 tv3 = *(const fx4*)(lt + 768 + 4 * lane);
    tv3 = m3 ? tv3 : zero;
    float ah = dot16(tv0, tv1, tv2, tv3, bbA);

    // ---- prefetch row1 (streams under row0's ~3000-cycle core) ----
    gll16(tg1 + 4 * lane,       lt);        // buffer fully read above; reuse safe
    gll16(tg1 + 256 + 4 * lane, lt + 256);  // (ds_read executes at issue; GLL write
    gll16(tg1 + 512 + 4 * lane, lt + 512);  //  lands when data returns, much later)
    gll16(tg1 + o3,             lt + 768);
    fx4 p0, p1, p2, p3;
    {
        const float* a0 = in1 + 4 * lane;
        const float* a1 = in1 + 256 + 4 * lane;
        const float* a2 = in1 + 512 + 4 * lane;
        const float* a3 = in1 + o3;
        asm volatile("global_load_dwordx4 %0, %1, off" : "=v"(p0) : "v"(a0));
        asm volatile("global_load_dwordx4 %0, %1, off" : "=v"(p1) : "v"(a1));
        asm volatile("global_load_dwordx4 %0, %1, off" : "=v"(p2) : "v"(a2));
        asm volatile("global_load_dwordx4 %0, %1, off" : "=v"(p3) : "v"(a3));
    }
    asm volatile("" ::: "memory");   // pin issue point before the core

    // ---- row0 core: 8 loads + 1 store outstanding underneath ----
    row_core(bbA, mx, ah, row_out, r0i, lane, true, C0, E_off, dE);

    // wait the 8 prefetch loads; vmcnt(1) leaves row0's (newest) store pending
    asm volatile("s_waitcnt vmcnt(1)"
                 : "+v"(p0), "+v"(p1), "+v"(p2), "+v"(p3) :: "memory");
    p3 = m3 ? p3 : xpad;
    mx = tr16(p0, p1, p2, p3, bbB);
    tv0 = *(const fx4*)(lt + 4 * lane);
    tv1 = *(const fx4*)(lt + 256 + 4 * lane);
    tv2 = *(const fx4*)(lt + 512 + 4 * lane);
    tv3 = *(const fx4*)(lt + 768 + 4 * lane);
    tv3 = m3 ? tv3 : zero;
    ah = dot16(tv0, tv1, tv2, tv3, bbB);

    row_core(bbB, mx, ah, row_out, r1i, lane, st1, C0, E_off, dE);
}

__global__ __launch_bounds__(1024) void reduce_mean(
    const float* __restrict__ row_out, float* __restrict__ out, int n)
{
    __shared__ double sm[16];
    const int lane = threadIdx.x & 63;
    const int wv   = threadIdx.x >> 6;
    const int n4   = n >> 2;
    const float4* r4 = (const float4*)row_out;
    double s = 0.0;
    for (int i = threadIdx.x; i < n4; i += 1024) {
        float4 v = r4[i];
        s += (double)v.x + (double)v.y + (double)v.z + (double)v.w;
    }
    if (threadIdx.x == 0)
        for (int i = n4 << 2; i < n; ++i) s += (double)row_out[i];
    #pragma unroll
    for (int off = 32; off > 0; off >>= 1) s += __shfl_xor(s, off, 64);
    if (lane == 0) sm[wv] = s;
    __syncthreads();
    if (wv == 0) {
        double t = (lane < 16) ? sm[lane] : 0.0;
        #pragma unroll
        for (int off = 32; off > 0; off >>= 1) t += __shfl_xor(t, off, 64);
        if (lane == 0) out[0] = (float)(t / (double)n);
    }
}

extern "C" void kernel_launch(void* const* d_in, const int* in_sizes, int n_in,
                              void* d_out, int out_size, void* d_ws, size_t ws_size,
                              hipStream_t stream) {
    const float* inputs  = (const float*)d_in[0];
    const float* targets = (const float*)d_in[1];
    float* out = (float*)d_out;

    const int N = in_sizes[0] / C_DIM;
    float* row_out = (float*)d_ws;

    // Smoothed one-hot targets take 2 values; per-elem loss = F - E*r4 + r9/1.8.
    // Row sum = C0 - E_off*S4 - (E_on-E_off)*r4_hot + S9/1.8, C0 = 999*F_off + F_on.
    const double ls    = 0.05;
    const double c1g_d = 1.0 - (1000.0 / 999.0) * ls;
    const double c2_d  = ls / 999.0;
    const float  tp_on_f  = (float)c1g_d + (float)c2_d;
    const float  tp_off_f = (float)c2_d;
    const double tp_on  = (double)tp_on_f;
    const double tp_off = (double)tp_off_f;
    const double A_on  = (pow(tp_on  + 1e-8, 0.8) - 1.0) / 0.8;
    const double A_off = (pow(tp_off + 1e-8, 0.8) - 1.0) / 0.8;
    const double B_on  = pow(tp_on,  1.8);
    const double B_off = pow(tp_off, 1.8);
    const double E_on_d  = 1.25 * tp_on;
    const double E_off_d = 1.25 * tp_off;
    const double F_on_d  = tp_on  * A_on  + E_on_d  - B_on  / 1.8;
    const double F_off_d = tp_off * A_off + E_off_d - B_off / 1.8;
    const double C0_d    = (C_DIM - 1) * F_off_d + F_on_d;
    const double dE_d    = E_on_d - E_off_d;

    dim3 grid((N + 7) / 8);
    btll<<<grid, 256, 0, stream>>>(inputs, targets, row_out, N,
                                   (float)C0_d, (float)E_off_d, (float)dE_d);
    reduce_mean<<<1, 1024, 0, stream>>>(row_out, out, N);
}